// Round 13
// baseline (144.901 us; speedup 1.0000x reference)
//
#include <hip/hip_runtime.h>
#include <math.h>

#define L_    4096
#define PS_   16
#define STR_  8
#define PC_   511   // (4096-16)/8 + 1
#define HID_  64
#define NBLK_ 2048  // B*C
#define WSTRIDE_ 512

typedef __bf16 bf16x8 __attribute__((ext_vector_type(8)));
typedef float  f32x4  __attribute__((ext_vector_type(4)));

// gelu tanh-form: x * sigmoid(2c(x + 0.044715 x^3)); |err| <= ~5e-4.
__device__ __forceinline__ float gelu_fast(float x) {
    float u = x * x;
    float t = fmaf(u, 0.10294294f, 2.3022082f);   // 2c*log2(e), pre-scaled
    float a = x * t;
    float e = __builtin_amdgcn_exp2f(a);
    float r = __builtin_amdgcn_rcpf(e + 1.0f);
    return fmaf(-x, r, x);                         // x*(1-r)
}

// ---------------- Kernel A: per-patch MLP -> ws[row][patch] = (dx, ds) ----------------
__global__ __launch_bounds__(256, 4) void mlp_kernel(
    const float* __restrict__ X,
    const float* __restrict__ W1,
    const float* __restrict__ b1,
    const float* __restrict__ W2,
    const float* __restrict__ b2,
    float2* __restrict__ ws)
{
    const int tid = threadIdx.x;
    const int bc  = blockIdx.x;
    const float* xrow = X + (size_t)bc * L_;

    const int l   = tid & 63;
    const int lr  = l & 15;        // patch within group / W1 A-frag row
    const int lq  = l >> 4;        // k-chunk / C-row quad
    const int lkb = lq * 8;

    bf16x8 afrag[4];
    f32x4  b1c[4];
    float  w2x[4][4], w2s[4][4];   // [nb][r] -> hid = nb*16 + lq*4 + r
    #pragma unroll
    for (int nb = 0; nb < 4; ++nb) {
        #pragma unroll
        for (int j = 0; j < 8; ++j) {
            int ks = lkb + j;
            afrag[nb][j] = (__bf16)((ks < PS_) ? W1[(nb * 16 + lr) * PS_ + ks] : 0.0f);
        }
        #pragma unroll
        for (int r = 0; r < 4; ++r) {
            int hid = nb * 16 + lq * 4 + r;
            b1c[nb][r] = b1[hid];
            w2x[nb][r] = W2[hid];
            w2s[nb][r] = W2[HID_ + hid];
        }
    }
    const float b20 = b2[0];
    const float b21 = b2[1];

    const int wave = tid >> 6;
    float2* wsrow = ws + (size_t)bc * WSTRIDE_;

    // B-frag straight from global: lane reads floats (g*16+lr+lq)*8 .. +7 (clamped in-row).
    auto ldfrag = [&](int g) -> bf16x8 {
        int off = ((g << 4) + lr + lq) << 3;
        off = min(off, L_ - 8);
        float4 v0 = *reinterpret_cast<const float4*>(xrow + off);
        float4 v1 = *reinterpret_cast<const float4*>(xrow + off + 4);
        bf16x8 r;
        r[0]=(__bf16)v0.x; r[1]=(__bf16)v0.y; r[2]=(__bf16)v0.z; r[3]=(__bf16)v0.w;
        r[4]=(__bf16)v1.x; r[5]=(__bf16)v1.y; r[6]=(__bf16)v1.z; r[7]=(__bf16)v1.w;
        return r;
    };

#define MLP_REDUCE(cA0, cA1, cA2, cA3, dxv, dsv)                         \
    {                                                                    \
        float dx0 = 0.0f, dx1 = 0.0f, ds0 = 0.0f, ds1 = 0.0f;            \
        _Pragma("unroll")                                                \
        for (int r = 0; r < 4; ++r) {                                    \
            float g0 = gelu_fast(cA0[r]);                                \
            float g1 = gelu_fast(cA1[r]);                                \
            float g2 = gelu_fast(cA2[r]);                                \
            float g3 = gelu_fast(cA3[r]);                                \
            dx0 = fmaf(g0, w2x[0][r], dx0);                              \
            dx0 = fmaf(g1, w2x[1][r], dx0);                              \
            dx1 = fmaf(g2, w2x[2][r], dx1);                              \
            dx1 = fmaf(g3, w2x[3][r], dx1);                              \
            ds0 = fmaf(g0, w2s[0][r], ds0);                              \
            ds0 = fmaf(g1, w2s[1][r], ds0);                              \
            ds1 = fmaf(g2, w2s[2][r], ds1);                              \
            ds1 = fmaf(g3, w2s[3][r], ds1);                              \
        }                                                                \
        float dx_ = dx0 + dx1, ds_ = ds0 + ds1;                          \
        dx_ += __shfl_xor(dx_, 16, 64);  ds_ += __shfl_xor(ds_, 16, 64); \
        dx_ += __shfl_xor(dx_, 32, 64);  ds_ += __shfl_xor(ds_, 32, 64); \
        dxv = dx_ + b20;  dsv = ds_ + b21;                               \
    }

    bf16x8 nA = ldfrag(wave * 8 + 0);
    bf16x8 nB = ldfrag(wave * 8 + 1);

    #pragma unroll
    for (int i = 0; i < 4; ++i) {
        const bf16x8 cA = nA, cB = nB;
        if (i < 3) {
            nA = ldfrag(wave * 8 + 2 * i + 2);
            nB = ldfrag(wave * 8 + 2 * i + 3);
        }
        f32x4 a0 = __builtin_amdgcn_mfma_f32_16x16x32_bf16(afrag[0], cA, b1c[0], 0, 0, 0);
        f32x4 a1 = __builtin_amdgcn_mfma_f32_16x16x32_bf16(afrag[1], cA, b1c[1], 0, 0, 0);
        f32x4 a2 = __builtin_amdgcn_mfma_f32_16x16x32_bf16(afrag[2], cA, b1c[2], 0, 0, 0);
        f32x4 a3 = __builtin_amdgcn_mfma_f32_16x16x32_bf16(afrag[3], cA, b1c[3], 0, 0, 0);
        f32x4 q0 = __builtin_amdgcn_mfma_f32_16x16x32_bf16(afrag[0], cB, b1c[0], 0, 0, 0);
        f32x4 q1 = __builtin_amdgcn_mfma_f32_16x16x32_bf16(afrag[1], cB, b1c[1], 0, 0, 0);
        f32x4 q2 = __builtin_amdgcn_mfma_f32_16x16x32_bf16(afrag[2], cB, b1c[2], 0, 0, 0);
        f32x4 q3 = __builtin_amdgcn_mfma_f32_16x16x32_bf16(afrag[3], cB, b1c[3], 0, 0, 0);

        float dxA, dsA, dxB, dsB;
        MLP_REDUCE(a0, a1, a2, a3, dxA, dsA)
        MLP_REDUCE(q0, q1, q2, q3, dxB, dsB)

        const int pA = wave * 128 + (2 * i) * 16 + lr;
        const int pB = pA + 16;
        if (lq == 0) {
            if (pA < PC_) wsrow[pA] = make_float2(dxA, dsA);
            if (pB < PC_) wsrow[pB] = make_float2(dxB, dsB);
        }
    }
#undef MLP_REDUCE
}

// ---------------- Kernel B: bilinear sampling from staged f32 row ----------------
__global__ __launch_bounds__(256, 4) void sample_kernel(
    const float* __restrict__ X,
    const float2* __restrict__ ws,
    float* __restrict__ out)
{
    __shared__ __attribute__((aligned(16))) float s_row[L_ + 32];

    const int tid = threadIdx.x;
    const int bc  = blockIdx.x;
    const float* xrow = X + (size_t)bc * L_;

    const int l  = tid & 63;
    const int lr = l & 15;
    const int lq = l >> 4;
    const int wave = tid >> 6;
    const float2* wsrow = ws + (size_t)bc * WSTRIDE_;

    // prefetch (dx,ds) for this lane's 8 patches BEFORE staging (latency overlap)
    float2 dd[8];
    #pragma unroll
    for (int gi = 0; gi < 8; ++gi) {
        int p = wave * 128 + gi * 16 + lr;
        dd[gi] = wsrow[min(p, PC_ - 1)];
    }

    {
        const float4* src4 = reinterpret_cast<const float4*>(xrow);
        float4* dst4 = reinterpret_cast<float4*>(s_row);
        #pragma unroll
        for (int i = 0; i < 4; ++i) dst4[tid + 256 * i] = src4[tid + 256 * i];
        if (tid < 32) s_row[L_ + tid] = 0.0f;
    }
    __syncthreads();

    const float t0 = (float)lq * (4.0f / 15.0f);
    float* obase = out + (size_t)bc * PC_ * PS_;

    #pragma unroll
    for (int gi = 0; gi < 8; ++gi) {
        const int p = wave * 128 + gi * 16 + lr;
        const float dx = dd[gi].x;
        const float ds = dd[gi].y;

        const float refp = (float)(p * STR_) + 7.5f;
        const float d2   = fmaxf(ds + 7.5f, 0.0f);
        const float aa   = dx + refp;
        const float loi  = fminf(fmaxf(aa - d2, 0.0f), 4095.0f);
        const float hii  = fminf(fmaxf(aa + d2, 0.0f), 4095.0f);
        const float span = hii - loi;

        float4 o;
        float* ov = reinterpret_cast<float*>(&o);
        #pragma unroll
        for (int si = 0; si < 4; ++si) {
            float t  = t0 + (float)si * (1.0f / 15.0f);
            float ix = fmaf(span, t, loi);
            float f  = floorf(ix);
            float wx = ix - f;
            int i0 = (int)f;
            float v0 = s_row[i0];
            float v1 = s_row[i0 + 1];          // i0==4095 -> pad, wx==0
            ov[si] = fmaf(wx, v1 - v0, v0);
        }
        if (p < PC_)
            *reinterpret_cast<float4*>(obase + (size_t)p * PS_ + lq * 4) = o;
    }
}

extern "C" void kernel_launch(void* const* d_in, const int* in_sizes, int n_in,
                              void* d_out, int out_size, void* d_ws, size_t ws_size,
                              hipStream_t stream) {
    const float* X  = (const float*)d_in[0];
    const float* W1 = (const float*)d_in[1];
    const float* b1 = (const float*)d_in[2];
    const float* W2 = (const float*)d_in[3];
    const float* b2 = (const float*)d_in[4];
    float* out = (float*)d_out;
    float2* ws = (float2*)d_ws;    // 2048 * 512 * 8 B = 8.4 MB

    mlp_kernel<<<dim3(NBLK_), dim3(256), 0, stream>>>(X, W1, b1, W2, b2, ws);
    sample_kernel<<<dim3(NBLK_), dim3(256), 0, stream>>>(X, ws, out);
}